// Round 4
// baseline (2674.356 us; speedup 1.0000x reference)
//
#include <hip/hip_runtime.h>
#include <hip/hip_bf16.h>

#define NT 1024
typedef unsigned short u16;
typedef unsigned long long u64;

__device__ __forceinline__ u16 tobf(float x) {
  union { __hip_bfloat16 h; u16 u; } cv;
  cv.h = __float2bfloat16(x);
  return cv.u;
}
__device__ __forceinline__ float frombf(u16 u) {
  return __uint_as_float(((unsigned)u) << 16);
}
__device__ __forceinline__ float sigf(float x) {
  return __builtin_amdgcn_rcpf(1.f + __builtin_amdgcn_exp2f(-1.4426950408889634f * x));
}
__device__ __forceinline__ float tanh_fast(float x) {
  return 1.f - 2.f * __builtin_amdgcn_rcpf(1.f + __builtin_amdgcn_exp2f(2.8853900817779268f * x));
}
// wave-local LDS ordering: waits this wave's ds ops, blocks compiler motion.
__device__ __forceinline__ void lds_fence() {
  asm volatile("s_waitcnt lgkmcnt(0)" ::: "memory");
  __builtin_amdgcn_sched_barrier(0);
}
// block barrier WITHOUT vmcnt(0) drain (LDS ordering only). Global stores drift.
__device__ __forceinline__ void bar_light() {
  asm volatile("s_waitcnt lgkmcnt(0)" ::: "memory");
  __builtin_amdgcn_s_barrier();
  asm volatile("" ::: "memory");
}

struct SeqArgs {
  const float* input;
  const float* nv1_0; const float* nv2_0; const float* nv1_1; const float* nv2_1;
  const float* w_start0; const float* b_start0; const float* w_mlp0; const float* b_mlp0;
  const float* w_end0;   const float* b_end0;   const float* w_lin0; const float* b_lin0;
  const float* gamma0;   const float* beta0;
  const float* w_start1; const float* b_start1; const float* w_mlp1; const float* b_mlp1;
  const float* w_end1;   const float* b_end1;   const float* w_lin1; const float* b_lin1;
  const float* gamma1;   const float* beta1;
  u64*   HCOL2;  // ws ring [16][192][192] of {f32 val, u32 tag}
  int*   prog;   // ws [192*32] ints, stride 32: consumer progress (backpressure)
  float* out_all; float* out_hrow; float* out_hcol;
};

// 1024 threads = 16 waves = 4 waves/SIMD (needs VGPR<=128).
__global__ __launch_bounds__(NT, 4) void seq_kernel(SeqArgs A) {
  const int n = blockIdx.x, w = n >> 3, b = n & 7, tid = threadIdx.x;
  const int pred = (n + 184) % 192;   // n-8 mod 192
  const int succ = (n + 8) % 192;

  __shared__ __align__(16) float sCIN[1152];    // [h_row(192) | h_col(192) | xbuf0(384) | xbuf1(384)]
  __shared__ __align__(16) u16   sWS[64 * 132]; // conv weights bf16, row=ich*16+c
  __shared__ __align__(16) float sAT[4096];     // aT[w*64+v]
  __shared__ __align__(16) float sH[2][1024];   // h0 / h1 rows [c*64+v]
  __shared__ __align__(16) float sAbuf[4928];
  float* const sPart = sAbuf;          // [0..3071] pre-conv partials (P*16*64)
  float* const sG    = sAbuf;          // [0..2047]
  float* const sH2c  = sAbuf + 2048;   // [2048..3071] h2 rows (dead after G)
  float* const sE    = sAbuf + 2048;   // [2048..2431] (overwrites dead h2)
  float* const sY    = sAbuf;          // [0..1151]   (overwrites dead sG)
  float* const smWE  = sAbuf + 3072;   // 192
  float* const smBE  = sAbuf + 3264;   // 6
  float* const smWM  = sAbuf + 3328;   // 32*50 (stride 50: bank-conflict-free)

  for (int layer = 0; layer < 2; ++layer) {
    const int in_dim = 3 + layer;
    const int P = in_dim - 1;  // pre channels: h_row + x-channels
    const float* nv1    = layer ? A.nv1_1    : A.nv1_0;
    const float* nv2    = layer ? A.nv2_1    : A.nv2_0;
    const float* wstart = layer ? A.w_start1 : A.w_start0;
    const float* bs     = layer ? A.b_start1 : A.b_start0;
    const float* wm     = layer ? A.w_mlp1   : A.w_mlp0;
    const float* bm     = layer ? A.b_mlp1   : A.b_mlp0;
    const float* we     = layer ? A.w_end1   : A.w_end0;
    const float* be     = layer ? A.b_end1   : A.b_end0;
    const float* wl     = layer ? A.w_lin1   : A.w_lin0;
    const float* bl     = layer ? A.b_lin1   : A.b_lin0;
    const float* gm     = layer ? A.gamma1   : A.gamma0;
    const float* bt     = layer ? A.beta1    : A.beta0;

    // ---- layer init: adjacency (scores -> softmax -> sAT), weights, regs ----
    for (int idx = tid; idx < 4096; idx += NT) {
      int v = idx >> 6, ww = idx & 63;
      float s = 0.f;
      for (int j = 0; j < 40; ++j) s = fmaf(nv1[v*40 + j], nv2[j*64 + ww], s);
      sAbuf[idx] = fmaxf(s, 0.f);
    }
    __syncthreads();
    if (tid < 64) {
      const int v = tid;
      float m = -1e30f;
      for (int ww = 0; ww < 64; ++ww) m = fmaxf(m, sAbuf[v*64 + ww]);
      float s = 0.f;
      for (int ww = 0; ww < 64; ++ww) { float e = expf(sAbuf[v*64 + ww] - m); sAbuf[v*64 + ww] = e; s += e; }
      float inv = 1.f / s, rs = 1.f;
      for (int ww = 0; ww < 64; ++ww) rs += sAbuf[v*64 + ww] * inv;
      float irs = 1.f / rs;
      for (int ww = 0; ww < 64; ++ww) {
        float a = sAbuf[v*64 + ww] * inv + ((ww == v) ? 1.f : 0.f);
        sAT[ww*64 + v] = a * irs;
      }
    }
    __syncthreads();  // sAT ready; scores region dead
    for (int idx = tid; idx < 16*in_dim*132; idx += NT) {
      int row = idx / 132, k = idx - row*132;
      sWS[idx] = (k < 129) ? tobf(wstart[((row & 15)*in_dim + (row >> 4))*129 + k]) : (u16)0;
    }
    for (int idx = tid; idx < 1536; idx += NT) { int o = idx/48, c = idx - o*48; smWM[o*50 + c] = wm[idx]; }
    for (int idx = tid; idx < 192; idx += NT) smWE[idx] = we[idx];
    if (tid < 6) smBE[tid] = be[tid];
    for (int d = tid; d < 384; d += NT) sCIN[d] = 0.f;

    const int v_p = tid & 63;
    const int o0  = tid >> 6;         // wave id, 0..15
    const float bmv0 = bm[o0], bmv1 = bm[o0 + 16];
    float blv = 0.f, gmv = 1.f, btv = 0.f;
    if (tid < 384) blv = bl[(tid >= 192) ? tid - 192 : tid];
    if (tid < 192) { gmv = gm[tid]; btv = bt[tid]; }
    const float bs_r0 = bs[o0];
    __syncthreads();

    // ---- conv+assemble of pre channels; x in xbuf[parity] ----
    auto pre_conv = [&](int parity) {
      const float* xb = &sCIN[384 + parity*384];
      const int nslots = P << 9;   // P*16*32 slots, 2 outputs each
      for (int s = tid; s < nslots; s += NT) {
        const int cidx = s >> 5;          // p*16+c
        const int vg2  = s & 31;
        const int p = cidx >> 4, c = cidx & 15;
        const int ich = (p == 0) ? 0 : (p + 1);
        const float* xin = ((p == 0) ? &sCIN[0] : &xb[(p-1)*192]) + vg2*2;
        const u16* wrow = &sWS[(ich*16 + c)*132];
        float a0 = 0.f, a1 = 0.f;
        float2 xc = *(const float2*)xin;
        for (int k2 = 0; k2 < 128; k2 += 2) {
          ushort2 wu = *(const ushort2*)(wrow + k2);
          float w0 = frombf(wu.x), w1 = frombf(wu.y);
          float2 xn = *(const float2*)(xin + k2 + 2);
          a0 = fmaf(w1, xc.y, fmaf(w0, xc.x, a0));
          a1 = fmaf(w1, xn.x, fmaf(w0, xc.y, a1));
          xc = xn;
        }
        float wk = frombf(wrow[128]);
        a0 = fmaf(wk, xc.x, a0); a1 = fmaf(wk, xc.y, a1);
        *(float2*)&sPart[cidx*64 + vg2*2] = make_float2(a0, a1);
      }
      bar_light();
      {
        const int c0 = o0, v = v_p;   // 16 rows, one per wave
        float sum = bs_r0;
        for (int p = 0; p < P; ++p) sum += sPart[(p*16 + c0)*64 + v];
        sH[0][c0*64 + v] = sum;
      }
      bar_light();
    };

    // ---- t=0 staging: x(0) -> xbuf0 ----
    {
      float* xb = &sCIN[384];
      if (layer == 0) {
        int o = 0 - w;
        if (o >= 0 && o < 48) {
          const float* xr = A.input + (((size_t)(b*24 + w)*48 + o)*192);
          for (int d = tid; d < 192; d += NT) xb[d] = xr[d];
        } else {
          for (int d = tid; d < 192; d += NT) xb[d] = 0.f;
        }
      } else {
        const float* xr = A.out_all + ((size_t)n*71 + 0)*384;
        for (int d = tid; d < 384; d += NT) xb[d] = xr[d];
      }
      bar_light();
      pre_conv(0);
    }

    for (int t = 0; t < 71; ++t) {
      const int S = layer*71 + t;

      // ---- dependent path: per-lane tagged poll (single round-trip) ----
      if (t > 0) {
        if (tid < 192) {
          const u64* src = &A.HCOL2[((size_t)((S-1) & 15)*192 + pred)*192 + tid];
          u64 v = __hip_atomic_load(src, __ATOMIC_RELAXED, __HIP_MEMORY_SCOPE_AGENT);
          while ((unsigned)(v >> 32) != (unsigned)S) {
            __builtin_amdgcn_s_sleep(1);
            v = __hip_atomic_load(src, __ATOMIC_RELAXED, __HIP_MEMORY_SCOPE_AGENT);
          }
          __builtin_amdgcn_sched_barrier(0);
          asm volatile("" ::: "memory");
          sCIN[192 + tid] = __uint_as_float((unsigned)v);
        }
        bar_light();  // Bp
        if (tid == 0)
          __hip_atomic_store(&A.prog[n*32], S, __ATOMIC_RELAXED, __HIP_MEMORY_SCOPE_AGENT);
      }

      // ---- phase A: waves 0-7 = dependent chain; waves 8-15 = x(t+1) loader ----
      if (tid < 512) {
        // h_col conv: wave o0 owns channels {2*o0, 2*o0+1}; 2 outputs/thread
        {
          const int c = tid >> 5, vg2 = tid & 31;
          const int vbase = c*64 + vg2*2;
          const float* xin = &sCIN[192 + vg2*2];
          const u16* wrow = &sWS[(16 + c)*132];
          float a0 = sH[0][vbase], a1 = sH[0][vbase + 1];
          float2 xc = *(const float2*)xin;
          for (int k2 = 0; k2 < 128; k2 += 2) {
            ushort2 wu = *(const ushort2*)(wrow + k2);
            float w0 = frombf(wu.x), w1 = frombf(wu.y);
            float2 xn = *(const float2*)(xin + k2 + 2);
            a0 = fmaf(w1, xc.y, fmaf(w0, xc.x, a0));
            a1 = fmaf(w1, xn.x, fmaf(w0, xc.y, a1));
            xc = xn;
          }
          float wk = frombf(wrow[128]);
          a0 = fmaf(wk, xc.x, a0); a1 = fmaf(wk, xc.y, a1);
          sH[0][vbase] = a0; sH[0][vbase + 1] = a1;
        }
        lds_fence();
        {
          const int c0 = o0 * 2;   // this wave's 2 rows (o0 in 0..7 here)
          float pa0 = 0.f, pa1 = 0.f;
          for (int w4 = 0; w4 < 64; w4 += 4) {
            float a0v = sAT[(w4+0)*64 + v_p];
            float a1v = sAT[(w4+1)*64 + v_p];
            float a2v = sAT[(w4+2)*64 + v_p];
            float a3v = sAT[(w4+3)*64 + v_p];
            float4 h0v = *(const float4*)&sH[0][ c0      *64 + w4];
            float4 h1v = *(const float4*)&sH[0][(c0 + 1 )*64 + w4];
            pa0 = fmaf(h0v.x, a0v, pa0); pa0 = fmaf(h0v.y, a1v, pa0);
            pa0 = fmaf(h0v.z, a2v, pa0); pa0 = fmaf(h0v.w, a3v, pa0);
            pa1 = fmaf(h1v.x, a0v, pa1); pa1 = fmaf(h1v.y, a1v, pa1);
            pa1 = fmaf(h1v.z, a2v, pa1); pa1 = fmaf(h1v.w, a3v, pa1);
          }
          float h0a = sH[0][ c0      *64 + v_p];
          float h0b = sH[0][(c0 + 1 )*64 + v_p];
          sH[1][ c0      *64 + v_p] = fmaf(0.95f, pa0, 0.05f * h0a);
          sH[1][(c0 + 1 )*64 + v_p] = fmaf(0.95f, pa1, 0.05f * h0b);
          lds_fence();
          float pb0 = 0.f, pb1 = 0.f;
          for (int w4 = 0; w4 < 64; w4 += 4) {
            float a0v = sAT[(w4+0)*64 + v_p];
            float a1v = sAT[(w4+1)*64 + v_p];
            float a2v = sAT[(w4+2)*64 + v_p];
            float a3v = sAT[(w4+3)*64 + v_p];
            float4 h0v = *(const float4*)&sH[1][ c0      *64 + w4];
            float4 h1v = *(const float4*)&sH[1][(c0 + 1 )*64 + w4];
            pb0 = fmaf(h0v.x, a0v, pb0); pb0 = fmaf(h0v.y, a1v, pb0);
            pb0 = fmaf(h0v.z, a2v, pb0); pb0 = fmaf(h0v.w, a3v, pb0);
            pb1 = fmaf(h1v.x, a0v, pb1); pb1 = fmaf(h1v.y, a1v, pb1);
            pb1 = fmaf(h1v.z, a2v, pb1); pb1 = fmaf(h1v.w, a3v, pb1);
          }
          sH2c[ c0      *64 + v_p] = fmaf(0.95f, pb0, 0.05f * h0a);
          sH2c[(c0 + 1 )*64 + v_p] = fmaf(0.95f, pb1, 0.05f * h0b);
        }
      } else {
        // waves 8-15: x(t+1) -> xbuf[(t+1)&1], plus ring backpressure
        if (t < 70) {
          const int d = tid - 512;
          float* xb = &sCIN[384 + ((t+1) & 1)*384];
          if (layer == 0) {
            if (d < 192) {
              int o = (t + 1) - w;
              xb[d] = (o >= 0 && o < 48)
                    ? A.input[(((size_t)(b*24 + w)*48 + o)*192) + d] : 0.f;
            }
          } else {
            if (d < 384) xb[d] = A.out_all[((size_t)n*71 + (t+1))*384 + d];
          }
        }
        if (tid == 960 && S >= 16) {
          while (__hip_atomic_load(&A.prog[succ*32], __ATOMIC_RELAXED, __HIP_MEMORY_SCOPE_AGENT) < S - 15)
            __builtin_amdgcn_s_sleep(2);
        }
      }
      bar_light();  // B3: h0/h1/h2 ready; x(t+1) staged

      // (g) G = bm + wm0 h0 + wm1 h1 + wm2 h2; exact GELU -> sG (2 rows/thread)
      {
        float g0 = bmv0, g1 = bmv1;
#pragma unroll
        for (int c = 0; c < 16; ++c) {
          float h0v = sH[0][c*64 + v_p];
          float h1v = sH[1][c*64 + v_p];
          float h2v = sH2c[c*64 + v_p];
          g0 = fmaf(smWM[ o0      *50 + c], h0v, fmaf(smWM[ o0      *50 + 16 + c], h1v, fmaf(smWM[ o0      *50 + 32 + c], h2v, g0)));
          g1 = fmaf(smWM[(o0+16 )*50 + c], h0v, fmaf(smWM[(o0+16 )*50 + 16 + c], h1v, fmaf(smWM[(o0+16 )*50 + 32 + c], h2v, g1)));
        }
        g0 = 0.5f * g0 * (1.f + erff(g0 * 0.70710678118654752f));
        g1 = 0.5f * g1 * (1.f + erff(g1 * 0.70710678118654752f));
        sG[ o0      *64 + v_p] = g0;
        sG[(o0+16 )*64 + v_p] = g1;
      }
      bar_light();  // B4 (h2 region now dead -> sE may overwrite)

      // (h) E = be + we @ G
      for (int idx = tid; idx < 384; idx += NT) {
        int o2 = idx >> 6, v = idx & 63;
        float acc = smBE[o2];
        for (int c = 0; c < 32; ++c) acc = fmaf(smWE[o2*32 + c], sG[c*64 + v], acc);
        sE[idx] = acc;
      }
      bar_light();  // B5

      // (i) Y = bl + E @ wl^T : 384 threads, 3 rows each
      if (tid < 384) {
        const int d  = (tid >= 192) ? tid - 192 : tid;
        const int r0 = (tid >= 192) ? 3 : 0;
        const float4* wrow = (const float4*)(wl + d*64);
        float y0 = blv, y1 = blv, y2 = blv;
        for (int q = 0; q < 16; ++q) {
          float4 wv = wrow[q];
          float4 e0 = *(const float4*)&sE[(r0+0)*64 + q*4];
          float4 e1 = *(const float4*)&sE[(r0+1)*64 + q*4];
          float4 e2 = *(const float4*)&sE[(r0+2)*64 + q*4];
          y0 = fmaf(e0.x,wv.x, fmaf(e0.y,wv.y, fmaf(e0.z,wv.z, fmaf(e0.w,wv.w, y0))));
          y1 = fmaf(e1.x,wv.x, fmaf(e1.y,wv.y, fmaf(e1.z,wv.z, fmaf(e1.w,wv.w, y1))));
          y2 = fmaf(e2.x,wv.x, fmaf(e2.y,wv.y, fmaf(e2.z,wv.z, fmaf(e2.w,wv.w, y2))));
        }
        sY[(r0+0)*192 + d] = y0;
        sY[(r0+1)*192 + d] = y1;
        sY[(r0+2)*192 + d] = y2;
      }
      bar_light();  // B6

      // (j1) LN stats -> sH[1][0..13]
      if (tid < 192) {
        const int r = tid >> 5, l32 = tid & 31;
        float sm = 0.f, sq = 0.f;
#pragma unroll
        for (int m = 0; m < 6; ++m) {
          float v = sY[r*192 + l32 + 32*m];
          sm += v; sq = fmaf(v, v, sq);
        }
#pragma unroll
        for (int off = 16; off >= 1; off >>= 1) {
          sm += __shfl_xor(sm, off);
          sq += __shfl_xor(sq, off);
        }
        if (l32 == 0) {
          float mu = sm * (1.f/192.f);
          float var = sq * (1.f/192.f) - mu*mu;
          sH[1][r] = mu;
          sH[1][8 + r] = rsqrtf(fmaxf(var, 0.f) + 1e-5f);
        }
      }
      bar_light();  // B7

      float hcn = 0.f;
      // (k1) col gates -> hcn -> tagged 8B store (no drain, no extra barrier)
      if (tid < 192) {
        const int d = tid;
        float y2 = fmaf((sY[2*192+d] - sH[1][2]) * sH[1][10], gmv, btv);
        float y3 = fmaf((sY[3*192+d] - sH[1][3]) * sH[1][11], gmv, btv);
        float y5 = fmaf((sY[5*192+d] - sH[1][5]) * sH[1][13], gmv, btv);
        float ugc = sigf(y2), ogc = sigf(y3), igc = tanh_fast(y5);
        float hc = sCIN[192 + d];
        hcn = tanh_fast(fmaf(ugc, igc, (1.f - ugc)*hc)) * ogc;
        u64 pk = ((u64)(unsigned)(S + 1) << 32) | (u64)__float_as_uint(hcn);
        __hip_atomic_store(&A.HCOL2[((size_t)(S & 15)*192 + n)*192 + d], pk,
                           __ATOMIC_RELAXED, __HIP_MEMORY_SCOPE_AGENT);
      }
      // (k2) row gates + outputs (off critical path)
      if (tid < 192) {
        const int d = tid;
        float y0 = fmaf((sY[0*192+d] - sH[1][0]) * sH[1][8],  gmv, btv);
        float y1 = fmaf((sY[1*192+d] - sH[1][1]) * sH[1][9],  gmv, btv);
        float y4 = fmaf((sY[4*192+d] - sH[1][4]) * sH[1][12], gmv, btv);
        float ugr = sigf(y0), ogr = sigf(y1), igr = tanh_fast(y4);
        float hr = sCIN[d];
        float hrn = tanh_fast(fmaf(ugr, igr, (1.f - ugr)*hr)) * ogr;
        sCIN[d] = hrn;
        float* oa = A.out_all + ((size_t)n*71 + t)*384;
        if (layer == 0) { oa[d] = hrn; oa[192 + d] = hcn; }
        else {
          const float* xbt = &sCIN[384 + (t & 1)*384];   // residual = layer-0 out
          oa[d] = hrn + xbt[d]; oa[192 + d] = hcn + xbt[192 + d];
        }
        if (t == 47 + w)
          A.out_hrow[(((size_t)b*2 + layer)*24 + w)*192 + d] = hrn;
        if (w == 23 && t >= 23)
          A.out_hcol[(((size_t)b*2 + layer)*48 + (t - 23))*192 + d] = hcn;
      }
      bar_light();  // B9: h_row updated
      if (t < 70) pre_conv((t + 1) & 1);
    } // t
    __syncthreads();  // full barrier: drain out_all stores before next layer reads
  } // layer
}

extern "C" void kernel_launch(void* const* d_in, const int* in_sizes, int n_in,
                              void* d_out, int out_size, void* d_ws, size_t ws_size,
                              hipStream_t stream) {
  (void)in_sizes; (void)n_in; (void)out_size; (void)ws_size;
  char* ws = (char*)d_ws;
  int* prog  = (int*)ws;                   // 24,576 B (192 x 128B)
  u64* HCOL2 = (u64*)(ws + 24576);         // 16*192*192*8 = 4,718,592 B
  // total ws: 4,743,168 B

  hipMemsetAsync(ws, 0, 24576 + 4718592, stream);  // zero prog + tags

  SeqArgs A;
  A.input    = (const float*)d_in[0];
  A.nv1_0    = (const float*)d_in[1];  A.nv2_0 = (const float*)d_in[2];
  A.w_start0 = (const float*)d_in[3];  A.b_start0 = (const float*)d_in[4];
  A.w_mlp0   = (const float*)d_in[5];  A.b_mlp0   = (const float*)d_in[6];
  A.w_end0   = (const float*)d_in[7];  A.b_end0   = (const float*)d_in[8];
  A.w_lin0   = (const float*)d_in[9];  A.b_lin0   = (const float*)d_in[10];
  A.gamma0   = (const float*)d_in[11]; A.beta0    = (const float*)d_in[12];
  A.nv1_1    = (const float*)d_in[13]; A.nv2_1 = (const float*)d_in[14];
  A.w_start1 = (const float*)d_in[15]; A.b_start1 = (const float*)d_in[16];
  A.w_mlp1   = (const float*)d_in[17]; A.b_mlp1   = (const float*)d_in[18];
  A.w_end1   = (const float*)d_in[19]; A.b_end1   = (const float*)d_in[20];
  A.w_lin1   = (const float*)d_in[21]; A.b_lin1   = (const float*)d_in[22];
  A.gamma1   = (const float*)d_in[23]; A.beta1    = (const float*)d_in[24];
  A.HCOL2 = HCOL2; A.prog = prog;
  A.out_all  = (float*)d_out;
  A.out_hrow = (float*)d_out + 5234688;
  A.out_hcol = (float*)d_out + 5308416;

  seq_kernel<<<192, NT, 0, stream>>>(A);
}